// Round 8
// baseline (201.663 us; speedup 1.0000x reference)
//
#include <hip/hip_runtime.h>

// SimpleRNN fused kernel for MI355X (gfx950).  B=32768, T=28, I=28, H=128, C=10.
//
// Transposed recurrence D[h][b] = W * S^T (A=W resident in VGPRs, B=S^T from
// LDS, D rows pack to b64 writes of row-major S[b][h]).
// MFMA 16x16x32 bf16 layouts (m89/m91/m120):
//   A: A[m=lane&15][k=(lane>>4)*8+j]   B: B[k=(lane>>4)*8+j][n=lane&15]
//   D: D[(lane>>4)*4+reg][lane&15]
//
// R8: ISSUE-PORT diet. Cross-round accounting (R1..R7 all ~245-287 CU-cyc per
// 16b x 32h wave-step regardless of occupancy/latency structure) shows the
// SIMD issue port is the binding resource; scalar Pade tanh ~60% of insts.
//  - tanh Pade(5,4) in PACKED fp32 (v_pk_mul/add/fma_f32), pairs aligned to
//    the MFMA acc quads (no marshalling); plain 4x v_rcp (no combined-rcp).
//  - ds_read_b128 for S and x frags (stride 136 / 904, 16B-aligned rows):
//    12 -> 7 DS issues per wave-step. Bank conflicts from these strides are
//    predicted HARMLESS (issue-bound, not DS-bound; R4 evidence).
// Keep R7 skeleton: whole-x staged once to LDS (no in-loop global), 16-row
// blocks, grid 2048, 4 blocks/CU, bias-as-MFMA-C, no spills at 48 persistent.

#define T_STEPS 28
#define S_STRIDE 136
#define X_STRIDE 904
#define XSLOTS 3136          // 16 rows * 784 f32 / 4 per dwordx4

typedef __attribute__((ext_vector_type(2))) float f32x2;
typedef __attribute__((ext_vector_type(4))) float f32x4;
typedef __attribute__((ext_vector_type(8))) short short8;
typedef __attribute__((ext_vector_type(4))) unsigned int uint4v;

#define MFMA16 __builtin_amdgcn_mfma_f32_16x16x32_bf16

__device__ __forceinline__ f32x2 pk_mul(f32x2 a, f32x2 b) {
  f32x2 d; asm("v_pk_mul_f32 %0, %1, %2" : "=v"(d) : "v"(a), "v"(b)); return d;
}
__device__ __forceinline__ f32x2 pk_add(f32x2 a, f32x2 b) {
  f32x2 d; asm("v_pk_add_f32 %0, %1, %2" : "=v"(d) : "v"(a), "v"(b)); return d;
}
__device__ __forceinline__ f32x2 pk_fma(f32x2 a, f32x2 b, f32x2 c) {
  f32x2 d; asm("v_pk_fma_f32 %0, %1, %2, %3" : "=v"(d) : "v"(a), "v"(b), "v"(c)); return d;
}

__device__ __forceinline__ unsigned pack2(float lo, float hi) {
#if __has_builtin(__builtin_amdgcn_cvt_pk_bf16_f32)
  auto p = __builtin_amdgcn_cvt_pk_bf16_f32(lo, hi);   // RNE pack, 1 inst
  return __builtin_bit_cast(unsigned, p);
#else
  unsigned a = __builtin_bit_cast(unsigned, lo);
  a += 0x7FFFu + ((a >> 16) & 1u);
  unsigned b = __builtin_bit_cast(unsigned, hi);
  b += 0x7FFFu + ((b >> 16) & 1u);
  return (a >> 16) | (b & 0xFFFF0000u);
#endif
}

__device__ __forceinline__ float bf2f(unsigned short s) {
  return __builtin_bit_cast(float, (unsigned)s << 16);
}

__device__ __forceinline__ short8 to_frag(f32x4 a, f32x4 b) {
  union { unsigned u[4]; short8 v; } r;
  r.u[0] = pack2(a[0], a[1]);
  r.u[1] = pack2(a[2], a[3]);
  r.u[2] = pack2(b[0], b[1]);
  r.u[3] = pack2(b[2], b[3]);
  return r.v;
}

__device__ __forceinline__ short8 load_frag128(const unsigned short* sp, int off) {
  uint4v d = *(const uint4v*)(sp + off);   // single ds_read_b128 (16B aligned)
  return __builtin_bit_cast(short8, d);
}

// Pade(5,4) tanh on f32x4 in packed-f32: 14 pk (2cyc) + 4 rcp + 4 med3.
// t = z(945+105z^2+z^4)/(945+420z^2+15z^4); den>=945 -> finite; med3 clamps.
__device__ __forceinline__ f32x4 tanh4(f32x4 z, f32x2 c945, f32x2 c105,
                                       f32x2 c420, f32x2 c15) {
  f32x2 z0 = {z[0], z[1]}, z1 = {z[2], z[3]};
  f32x2 x0 = pk_mul(z0, z0), x1 = pk_mul(z1, z1);
  f32x2 p0 = pk_fma(x0, pk_add(x0, c105), c945);
  f32x2 p1 = pk_fma(x1, pk_add(x1, c105), c945);
  f32x2 q0 = pk_fma(x0, pk_fma(x0, c15, c420), c945);
  f32x2 q1 = pk_fma(x1, pk_fma(x1, c15, c420), c945);
  f32x2 n0 = pk_mul(z0, p0), n1 = pk_mul(z1, p1);
  f32x2 i0, i1;
  i0[0] = __builtin_amdgcn_rcpf(q0[0]);
  i0[1] = __builtin_amdgcn_rcpf(q0[1]);
  i1[0] = __builtin_amdgcn_rcpf(q1[0]);
  i1[1] = __builtin_amdgcn_rcpf(q1[1]);
  f32x2 t0 = pk_mul(n0, i0), t1 = pk_mul(n1, i1);
  f32x4 out;
  out[0] = __builtin_amdgcn_fmed3f(t0[0], -1.0f, 1.0f);
  out[1] = __builtin_amdgcn_fmed3f(t0[1], -1.0f, 1.0f);
  out[2] = __builtin_amdgcn_fmed3f(t1[0], -1.0f, 1.0f);
  out[3] = __builtin_amdgcn_fmed3f(t1[1], -1.0f, 1.0f);
  return out;
}

__global__ __launch_bounds__(256, 4) void rnn_fused(
    const float* __restrict__ x,  const float* __restrict__ Uw,
    const float* __restrict__ Ub, const float* __restrict__ Ww,
    const float* __restrict__ Wb, const float* __restrict__ Vw,
    const float* __restrict__ Vb, float* __restrict__ out) {
  __shared__ __align__(16) unsigned short Sbuf[2][16 * S_STRIDE];
  __shared__ __align__(16) unsigned short Xbuf[16 * X_STRIDE];

  const int tid  = threadIdx.x;
  const int w    = tid >> 6;
  const int lane = tid & 63;
  const int l15  = lane & 15;
  const int q    = lane >> 4;           // 0..3
  const int mrow = w * 32;              // h base for this wave (2 m-tiles)
  const int b0   = blockIdx.x * 16;

  const f32x4 zero4 = {0.f, 0.f, 0.f, 0.f};
  const f32x2 c945 = {945.f, 945.f}, c105 = {105.f, 105.f};
  const f32x2 c420 = {420.f, 420.f}, c15  = {15.f, 15.f};
  const float* xblk = x + (size_t)b0 * 784;

  // ---- prologue A: stage the whole x block -> Xbuf (bf16, k-padded) ----
  // slot s (dwordx4 of f32): global flat offset s*4 (fully coalesced).
  // LDS: row=s/196, g=s%196, t=g/7, j=g%7 -> row*904 + t*32 + j*4.
  {
    f32x4 xr[13];
#pragma unroll
    for (int k = 0; k < 13; ++k) {
      int s = tid + 256 * k;
      if (s < XSLOTS) xr[k] = *(const f32x4*)(xblk + s * 4);
    }
#pragma unroll
    for (int k = 0; k < 13; ++k) {
      int s = tid + 256 * k;
      if (s < XSLOTS) {
        int row = s / 196, g = s - row * 196, tt = g / 7, j = g - tt * 7;
        uint2 d; d.x = pack2(xr[k][0], xr[k][1]); d.y = pack2(xr[k][2], xr[k][3]);
        *(uint2*)(Xbuf + row * X_STRIDE + tt * 32 + j * 4) = d;
        if (j == 0) {   // zero k=28..31 once per (row,t)
          uint2 zz; zz.x = 0u; zz.y = 0u;
          *(uint2*)(Xbuf + row * X_STRIDE + tt * 32 + 28) = zz;
        }
      }
    }
  }

  // ---- prologue B: persistent weight fragments (after staging regs die) ----
  short8 wfrag[2][4];   // [mt][kt]
  short8 ufrag[2];      // [mt], K=32 padded (k>=28 zeroed)
  f32x4  bias[2];       // Ub[h]+Wb[h] at D rows h = mrow + mt*16 + q*4 + r
#pragma unroll
  for (int mt = 0; mt < 2; ++mt) {
    const int h = mrow + mt * 16 + l15;
    const float* wp = Ww + h * 128 + q * 8;
#pragma unroll
    for (int kt = 0; kt < 4; ++kt) {
      wfrag[mt][kt] = to_frag(*(const f32x4*)wp, *(const f32x4*)(wp + 4));
      wp += 32;
    }
    const float* up = Uw + h * 28 + q * 8;
    f32x4 u0 = *(const f32x4*)up;
    f32x4 u1 = zero4;
    if (q < 3) u1 = *(const f32x4*)(up + 4);
    ufrag[mt] = to_frag(u0, u1);
    const int hb = mrow + mt * 16 + q * 4;
    bias[mt] = *(const f32x4*)(Wb + hb) + *(const f32x4*)(Ub + hb);
  }
  __syncthreads();   // Xbuf visible

  const int ro = l15 * S_STRIDE;                 // S row base (batch = l15)
  const int xo = l15 * X_STRIDE + q * 8;         // x frag base
  f32x4 acc[2];

  // ---- t = 0 (S=0: projection only) ----
  {
    short8 xf = load_frag128(&Xbuf[0], xo);
    unsigned short* wp = &Sbuf[1][0];
#pragma unroll
    for (int mt = 0; mt < 2; ++mt) {
      f32x4 d0 = MFMA16(ufrag[mt], xf, bias[mt], 0, 0, 0);
      f32x4 t0 = tanh4(d0, c945, c105, c420, c15);
      uint2 dd; dd.x = pack2(t0[0], t0[1]); dd.y = pack2(t0[2], t0[3]);
      *(uint2*)(wp + ro + mrow + mt * 16 + q * 4) = dd;
    }
  }
  __syncthreads();

  // ---- t = 1 .. 27 : pure LDS/MFMA/VALU, zero global ----
#pragma unroll 1
  for (int t = 1; t < T_STEPS; ++t) {
    short8 xf = load_frag128(&Xbuf[0], xo + t * 32);

    const unsigned short* sp = &Sbuf[t & 1][0] + ro + q * 8;

    // kt = 0 with bias as C-operand
    short8 sA = load_frag128(sp, 0);
#pragma unroll
    for (int mt = 0; mt < 2; ++mt)
      acc[mt] = MFMA16(wfrag[mt][0], sA, bias[mt], 0, 0, 0);
#pragma unroll
    for (int kt = 1; kt < 4; ++kt) {
      sA = load_frag128(sp, kt * 32);
#pragma unroll
      for (int mt = 0; mt < 2; ++mt)
        acc[mt] = MFMA16(wfrag[mt][kt], sA, acc[mt], 0, 0, 0);
    }
#pragma unroll
    for (int mt = 0; mt < 2; ++mt)
      acc[mt] = MFMA16(ufrag[mt], xf, acc[mt], 0, 0, 0);

    unsigned short* wp = &Sbuf[(t + 1) & 1][0];
#pragma unroll
    for (int mt = 0; mt < 2; ++mt) {
      f32x4 th = tanh4(acc[mt], c945, c105, c420, c15);
      uint2 dd; dd.x = pack2(th[0], th[1]); dd.y = pack2(th[2], th[3]);
      *(uint2*)(wp + ro + mrow + mt * 16 + q * 4) = dd;
    }
    __syncthreads();
  }

  // ---- epilogue: out[b][c] = sum_h S[b][h]*Vw[c][h] + Vb[c] ----
  // Final S in Sbuf[0]. 16 rows x 10 cols per block.
  {
    const int r  = tid >> 4;        // 0..15
    const int c0 = tid & 15;        // 0..15; only c0<10 active
    if (c0 < 10) {
      const float* v0 = Vw + c0 * 128;
      const unsigned short* srow = &Sbuf[0][0] + r * S_STRIDE;
      float a0 = 0.f;
#pragma unroll 8
      for (int h = 0; h < 128; ++h) a0 += bf2f(srow[h]) * v0[h];
      out[(size_t)(b0 + r) * 10 + c0] = a0 + Vb[c0];
    }
  }
}

extern "C" void kernel_launch(void* const* d_in, const int* in_sizes, int n_in,
                              void* d_out, int out_size, void* d_ws, size_t ws_size,
                              hipStream_t stream) {
  const float* x  = (const float*)d_in[0];
  const float* Uw = (const float*)d_in[1];
  const float* Ub = (const float*)d_in[2];
  const float* Ww = (const float*)d_in[3];
  const float* Wb = (const float*)d_in[4];
  const float* Vw = (const float*)d_in[5];
  const float* Vb = (const float*)d_in[6];
  rnn_fused<<<2048, 256, 0, stream>>>(x, Uw, Ub, Ww, Wb, Vw, Vb, (float*)d_out);
}